// Round 3
// baseline (329.606 us; speedup 1.0000x reference)
//
#include <hip/hip_runtime.h>
#include <math.h>

#define SEQ 4096
#define DMODEL 1024
#define NH 16
#define DK 64
#define LDP 72   // padded LDS row (16-bit elems): conflict-free b64/b128 frag reads

typedef __bf16    bf16x8 __attribute__((ext_vector_type(8)));
typedef float     f32x4  __attribute__((ext_vector_type(4)));
typedef __fp16    fp16x2 __attribute__((ext_vector_type(2)));
typedef _Float16  h16x2  __attribute__((ext_vector_type(2)));
typedef _Float16  h16x4  __attribute__((ext_vector_type(4)));
typedef _Float16  h16x8  __attribute__((ext_vector_type(8)));

// global->LDS DMA, 16 B per lane; LDS dest = uniform base + lane*16 (no pad!)
#define GLOAD_LDS16(g, l) __builtin_amdgcn_global_load_lds(                     \
    (const __attribute__((address_space(1))) unsigned int*)(g),                 \
    (__attribute__((address_space(3))) unsigned int*)(l), 16, 0, 0)

// packed f32->f16 (RTZ), re-typed to _Float16x2
__device__ __forceinline__ h16x2 cvt_pk_h16(float a, float b) {
    fp16x2 r = __builtin_amdgcn_cvt_pkrtz(a, b);
    return __builtin_bit_cast(h16x2, r);
}

// ---------------------------------------------------------------------------
// Convert x (4M) + Wq/Wk/Wv/Wo (1M each) fp32 -> bf16 into contiguous ws.
// ---------------------------------------------------------------------------
__global__ __launch_bounds__(256)
void cvt_all(const float* __restrict__ x, const float* __restrict__ Wq,
             const float* __restrict__ Wk, const float* __restrict__ Wv,
             const float* __restrict__ Wo, __bf16* __restrict__ dst)
{
    const size_t M1 = 1u << 20;
    const size_t e = ((size_t)blockIdx.x * 256 + threadIdx.x) * 8;
    const float* src; size_t off;
    if      (e < 4*M1) { src = x;  off = e;        }
    else if (e < 5*M1) { src = Wq; off = e - 4*M1; }
    else if (e < 6*M1) { src = Wk; off = e - 5*M1; }
    else if (e < 7*M1) { src = Wv; off = e - 6*M1; }
    else               { src = Wo; off = e - 7*M1; }
    const float4 f0 = *reinterpret_cast<const float4*>(&src[off]);
    const float4 f1 = *reinterpret_cast<const float4*>(&src[off + 4]);
    bf16x8 pk;
    pk[0]=(__bf16)f0.x; pk[1]=(__bf16)f0.y; pk[2]=(__bf16)f0.z; pk[3]=(__bf16)f0.w;
    pk[4]=(__bf16)f1.x; pk[5]=(__bf16)f1.y; pk[6]=(__bf16)f1.z; pk[7]=(__bf16)f1.w;
    *reinterpret_cast<bf16x8*>(&dst[e]) = pk;
}

// ---------------------------------------------------------------------------
// 128x128 GEMM core with global_load_lds staging (XOR chunk swizzle).
// ---------------------------------------------------------------------------
__device__ __forceinline__ void gemm_core128(const __bf16* __restrict__ A,
                                             const __bf16* __restrict__ W,
                                             int m0, int n0, int t,
                                             __bf16* AsF, __bf16* BsF,
                                             f32x4 acc[4][4])
{
    const int w = t >> 6, lane = t & 63, l15 = lane & 15, quad = lane >> 4;
    const int wm = (w & 1) * 64, wn = (w >> 1) * 64;
    const int lr = lane >> 3, lc = lane & 7;
    for (int k0 = 0; k0 < DMODEL; k0 += 64) {
        __syncthreads();
        #pragma unroll
        for (int p = 0; p < 4; ++p) {
            const int n = w*4 + p;
            const int r = n*8 + lr;
            const int cl = lc ^ (r & 7);
            GLOAD_LDS16(&A[(size_t)(m0 + r) * DMODEL + k0 + cl*8], &AsF[n*512]);
            GLOAD_LDS16(&W[(size_t)(n0 + r) * DMODEL + k0 + cl*8], &BsF[n*512]);
        }
        __syncthreads();
        #pragma unroll
        for (int kb = 0; kb < 2; ++kb) {
            const int phys = ((kb*4 + quad) ^ (l15 & 7)) * 8;
            bf16x8 af[4], bfr[4];
            #pragma unroll
            for (int i = 0; i < 4; ++i) {
                af[i]  = *reinterpret_cast<const bf16x8*>(&AsF[(wm + i*16 + l15)*64 + phys]);
                bfr[i] = *reinterpret_cast<const bf16x8*>(&BsF[(wn + i*16 + l15)*64 + phys]);
            }
            #pragma unroll
            for (int ms = 0; ms < 4; ++ms)
                #pragma unroll
                for (int ns = 0; ns < 4; ++ns)
                    acc[ms][ns] = __builtin_amdgcn_mfma_f32_16x16x32_bf16(af[ms], bfr[ns], acc[ms][ns], 0, 0, 0);
        }
    }
}

// ---------------------------------------------------------------------------
// Fused QKV projection -> fp16. [0,1024)=Q scaled 0.125*log2e; [1024,2048)=K;
// [2048,3072)=V transposed Vt[d][s]. Q/K epilogue via per-wave LDS transpose.
// ---------------------------------------------------------------------------
__global__ __launch_bounds__(256, 3)
void gemm_qkv(const __bf16* __restrict__ xb, const __bf16* __restrict__ Wcat,
              const float* __restrict__ bq, const float* __restrict__ bk,
              const float* __restrict__ bv,
              _Float16* __restrict__ Qh, _Float16* __restrict__ Kh, _Float16* __restrict__ Vth)
{
    __shared__ __bf16 SM[4*64*LDP];      // staging uses first 32 KB
    __bf16* AsF = SM;
    __bf16* BsF = SM + 8192;
    const int t = threadIdx.x;
    const int n0g = blockIdx.x * 128;
    const int m0  = blockIdx.y * 128;
    const int which = n0g >> 10;
    const int n_in  = n0g & 1023;

    f32x4 acc[4][4] = {};
    gemm_core128(xb, Wcat, m0, n0g, t, AsF, BsF, acc);

    const int w = t >> 6, lane = t & 63, l15 = lane & 15, quad = lane >> 4;
    const int wm = (w & 1) * 64, wn = (w >> 1) * 64;
    const float* bias = (which == 0) ? bq : (which == 1) ? bk : bv;
    float br[4];
    #pragma unroll
    for (int ns = 0; ns < 4; ++ns) br[ns] = bias[n_in + wn + ns*16 + l15];

    if (which == 2) {
        #pragma unroll
        for (int ms = 0; ms < 4; ++ms)
            #pragma unroll
            for (int ns = 0; ns < 4; ++ns) {
                h16x4 pk;
                #pragma unroll
                for (int rg = 0; rg < 4; ++rg) pk[rg] = (_Float16)(acc[ms][ns][rg] + br[ns]);
                *reinterpret_cast<h16x4*>(
                    &Vth[(size_t)(n_in + wn + ns*16 + l15) * SEQ + m0 + wm + ms*16 + quad*4]) = pk;
            }
    } else {
        const float s = (which == 0) ? 0.1803368787f : 1.0f;  // 0.125 * log2(e)
        _Float16* C = (which == 0) ? Qh : Kh;
        __syncthreads();   // all waves done with staging LDS
        _Float16* tile = (_Float16*)SM + w * 64 * LDP;   // per-wave 64x72 region
        #pragma unroll
        for (int ms = 0; ms < 4; ++ms)
            #pragma unroll
            for (int ns = 0; ns < 4; ++ns)
                #pragma unroll
                for (int rg = 0; rg < 4; ++rg)
                    tile[(ms*16 + quad*4 + rg) * LDP + ns*16 + l15] =
                        (_Float16)((acc[ms][ns][rg] + br[ns]) * s);
        asm volatile("s_waitcnt lgkmcnt(0)" ::: "memory");   // same-wave drain
        const int er = lane >> 3, ec = (lane & 7) * 8;
        #pragma unroll
        for (int p = 0; p < 8; ++p) {
            const h16x8 v = *reinterpret_cast<const h16x8*>(&tile[(er + p*8) * LDP + ec]);
            *reinterpret_cast<h16x8*>(
                &C[(size_t)(m0 + wm + er + p*8) * DMODEL + n_in + wn + ec]) = v;
        }
    }
}

// ---------------------------------------------------------------------------
// 128x64 GEMM core with DMA staging, for the output projection.
// ---------------------------------------------------------------------------
__device__ __forceinline__ void gemm_core64(const __bf16* __restrict__ A,
                                            const __bf16* __restrict__ W,
                                            int m0, int n0, int t,
                                            __bf16* AsF, __bf16* BsF,
                                            f32x4 acc[2][4])
{
    const int w = t >> 6, lane = t & 63, l15 = lane & 15, quad = lane >> 4;
    const int lr = lane >> 3, lc = lane & 7;
    for (int k0 = 0; k0 < DMODEL; k0 += 64) {
        __syncthreads();
        #pragma unroll
        for (int p = 0; p < 4; ++p) {
            const int n = w*4 + p;
            const int r = n*8 + lr;
            const int cl = lc ^ (r & 7);
            GLOAD_LDS16(&A[(size_t)(m0 + r) * DMODEL + k0 + cl*8], &AsF[n*512]);
        }
        #pragma unroll
        for (int p = 0; p < 2; ++p) {
            const int n = w*2 + p;
            const int r = n*8 + lr;
            const int cl = lc ^ (r & 7);
            GLOAD_LDS16(&W[(size_t)(n0 + r) * DMODEL + k0 + cl*8], &BsF[n*512]);
        }
        __syncthreads();
        #pragma unroll
        for (int kb = 0; kb < 2; ++kb) {
            const int phys = ((kb*4 + quad) ^ (l15 & 7)) * 8;
            bf16x8 af0 = *reinterpret_cast<const bf16x8*>(&AsF[(w*32 + l15)*64 + phys]);
            bf16x8 af1 = *reinterpret_cast<const bf16x8*>(&AsF[(w*32 + 16 + l15)*64 + phys]);
            #pragma unroll
            for (int ns = 0; ns < 4; ++ns) {
                const bf16x8 bfr = *reinterpret_cast<const bf16x8*>(&BsF[(ns*16 + l15)*64 + phys]);
                acc[0][ns] = __builtin_amdgcn_mfma_f32_16x16x32_bf16(af0, bfr, acc[0][ns], 0, 0, 0);
                acc[1][ns] = __builtin_amdgcn_mfma_f32_16x16x32_bf16(af1, bfr, acc[1][ns], 0, 0, 0);
            }
        }
    }
}

__global__ __launch_bounds__(256, 4)
void gemm_out(const __bf16* __restrict__ Ob, const __bf16* __restrict__ Wob,
              const float* __restrict__ bo, float* __restrict__ out)
{
    __shared__ __bf16 AsF[128*64];
    __shared__ __bf16 BsF[64*64];
    const int t = threadIdx.x;
    const int n0 = blockIdx.x * 64;
    const int m0 = blockIdx.y * 128;

    f32x4 acc[2][4] = {};
    gemm_core64(Ob, Wob, m0, n0, t, AsF, BsF, acc);

    const int lane = t & 63, l15 = lane & 15, quad = lane >> 4, w = t >> 6;
    float br[4];
    #pragma unroll
    for (int ns = 0; ns < 4; ++ns) br[ns] = bo[n0 + ns*16 + l15];
    #pragma unroll
    for (int ms = 0; ms < 2; ++ms)
        #pragma unroll
        for (int ns = 0; ns < 4; ++ns)
            #pragma unroll
            for (int rg = 0; rg < 4; ++rg)
                out[(size_t)(m0 + w*32 + ms*16 + quad*4 + rg) * DMODEL + n0 + ns*16 + l15] =
                    acc[ms][ns][rg] + br[ns];
}

// ---------------------------------------------------------------------------
// Causal flash attention, V3: NO LDS, NO BARRIERS. K A-frags and V B-frags
// are loaded per-wave directly from global (addresses derived from the V2 LDS
// decode): ak = K[(j0+st*16+l15)*DM + h*64 + kb*32 + quad*8] (16B),
// bv = Vt[(h*64+ds*16+l15)*SEQ + j0 + st*16 + quad*4] (8B). The 4-wave
// duplication is served by L1/L2/L3 (all of K/V/Q = 24 MB, L3-resident;
// one head's K+V = 2 MB fits an XCD L2). Waves free-run: no per-tile
// __syncthreads lockstep, no vmcnt(0) drains, no LDS bank conflicts.
// Softmax: sum-only base-2, denominator via ones-B MFMA (accl row map = acc).
// Unit map (u in [0,48)), each CU's 3 units sum to 66 iterations:
//   u<16 : qt=16+u, g=0  (32 tiles)
//   u<32 : qt=u,    g=1  (qt in [16,32), 2qt-30 tiles, ascending)
//   u<48 : qt=47-u, g=0  single-chunk (2qt+2 tiles, descending)
// qt<16: normalize in-kernel -> bf16 Ob. qt>=16: fp32 partials -> part
// (d_out scratch, 512 units x 32 KB = exactly 16 MB) + row sums -> lpart.
// ---------------------------------------------------------------------------
__global__ __launch_bounds__(256, 3)
void attn_mfma(const _Float16* __restrict__ Q, const _Float16* __restrict__ K,
               const _Float16* __restrict__ Vt, __bf16* __restrict__ O,
               float* __restrict__ part, float* __restrict__ lpart)
{
    const int t = threadIdx.x;
    const int w = t >> 6;
    const int lane = t & 63, l15 = lane & 15, quad = lane >> 4;
    const int h = blockIdx.y;
    const int u = blockIdx.x;
    int qt, g;
    if      (u < 16) { qt = 16 + u; g = 0; }
    else if (u < 32) { qt = u;      g = 1; }
    else             { qt = 47 - u; g = 0; }
    const int tstart = g * 32;
    const int tlast  = 2*qt + 1;
    const int tend   = (tlast < tstart + 31) ? tlast : (tstart + 31);
    const int s0 = qt*128 + w*16;        // slice0 row base
    const int s1 = s0 + 64;              // slice1 row base

    // Q B-frags (x32: lane n=q=l15 holds d=quad*8+j), both slices, loaded once.
    h16x8 bq8[2][2];
    #pragma unroll
    for (int kb = 0; kb < 2; ++kb) {
        bq8[0][kb] = *reinterpret_cast<const h16x8*>(
            &Q[(size_t)(s0 + l15) * DMODEL + h*DK + kb*32 + quad*8]);
        bq8[1][kb] = *reinterpret_cast<const h16x8*>(
            &Q[(size_t)(s1 + l15) * DMODEL + h*DK + kb*32 + quad*8]);
    }

    // Per-lane frag base pointers (advance per tile).
    const _Float16* kp[4];
    const _Float16* vp[4];
    #pragma unroll
    for (int st = 0; st < 4; ++st)
        kp[st] = &K[(size_t)(tstart*64 + st*16 + l15) * DMODEL + h*DK + quad*8];
    #pragma unroll
    for (int ds_ = 0; ds_ < 4; ++ds_)
        vp[ds_] = &Vt[(size_t)(h*DK + ds_*16 + l15) * SEQ + tstart*64 + quad*4];

    f32x4 acc[2][4] = {};        // [slice][dsub]; C: col=d=l15, row=q=quad*4+rg
    f32x4 accl[2] = {};          // denom rowsums via ones-MFMA (same row map)
    const h16x4 vone = {(_Float16)1.f, (_Float16)1.f, (_Float16)1.f, (_Float16)1.f};

    for (int tk = tstart; tk <= tend; ++tk) {
        const int j0 = tk * 64;
        const bool act0 = (j0 <= s0 + 15);   // slice0 still in causal range
        const bool msk0 = (j0 + 63 > s0);
        const bool msk1 = (j0 + 63 > s1);
        const int rel0 = s0 - j0 + l15;
        const int rel1 = s1 - j0 + l15;

        // ---- issue all frag loads for this tile up front (24 loads/lane) ----
        h16x8 ak0v[4], ak1v[4];
        h16x4 bvv[4][4];
        #pragma unroll
        for (int st = 0; st < 4; ++st) {
            ak0v[st] = *reinterpret_cast<const h16x8*>(kp[st]);
            ak1v[st] = *reinterpret_cast<const h16x8*>(kp[st] + 32);
            kp[st] += (size_t)64 * DMODEL;
        }
        #pragma unroll
        for (int ds_ = 0; ds_ < 4; ++ds_) {
            #pragma unroll
            for (int st = 0; st < 4; ++st)
                bvv[ds_][st] = *reinterpret_cast<const h16x4*>(vp[ds_] + st*16);
            vp[ds_] += 64;
        }

        // ---- S^T = K . Q^T (x32); K A-frags shared by both slices ----
        h16x4 ap[2][4];
        #pragma unroll
        for (int st = 0; st < 4; ++st) {
            // slice 1 (always active)
            {
                f32x4 cc = {0.f, 0.f, 0.f, 0.f};
                cc = __builtin_amdgcn_mfma_f32_16x16x32_f16(ak0v[st], bq8[1][0], cc, 0, 0, 0);
                cc = __builtin_amdgcn_mfma_f32_16x16x32_f16(ak1v[st], bq8[1][1], cc, 0, 0, 0);
                float pv[4];
                #pragma unroll
                for (int rg = 0; rg < 4; ++rg) {
                    float e = exp2f(cc[rg]);
                    if (msk1 && (st*16 + quad*4 + rg > rel1)) e = 0.f;
                    pv[rg] = e;
                }
                const h16x2 lo = cvt_pk_h16(pv[0], pv[1]);
                const h16x2 hi = cvt_pk_h16(pv[2], pv[3]);
                ap[1][st] = (h16x4){lo[0], lo[1], hi[0], hi[1]};
                accl[1] = __builtin_amdgcn_mfma_f32_16x16x16f16(ap[1][st], vone, accl[1], 0, 0, 0);
            }
            // slice 0
            if (act0) {
                f32x4 cc = {0.f, 0.f, 0.f, 0.f};
                cc = __builtin_amdgcn_mfma_f32_16x16x32_f16(ak0v[st], bq8[0][0], cc, 0, 0, 0);
                cc = __builtin_amdgcn_mfma_f32_16x16x32_f16(ak1v[st], bq8[0][1], cc, 0, 0, 0);
                float pv[4];
                #pragma unroll
                for (int rg = 0; rg < 4; ++rg) {
                    float e = exp2f(cc[rg]);
                    if (msk0 && (st*16 + quad*4 + rg > rel0)) e = 0.f;
                    pv[rg] = e;
                }
                const h16x2 lo = cvt_pk_h16(pv[0], pv[1]);
                const h16x2 hi = cvt_pk_h16(pv[2], pv[3]);
                ap[0][st] = (h16x4){lo[0], lo[1], hi[0], hi[1]};
                accl[0] = __builtin_amdgcn_mfma_f32_16x16x16f16(ap[0][st], vone, accl[0], 0, 0, 0);
            }
        }

        // ---- O^ += P . V (x16); V B-frags shared by both slices ----
        #pragma unroll
        for (int ds_ = 0; ds_ < 4; ++ds_) {
            #pragma unroll
            for (int st = 0; st < 4; ++st) {
                acc[1][ds_] = __builtin_amdgcn_mfma_f32_16x16x16f16(ap[1][st], bvv[ds_][st], acc[1][ds_], 0, 0, 0);
                if (act0)
                    acc[0][ds_] = __builtin_amdgcn_mfma_f32_16x16x16f16(ap[0][st], bvv[ds_][st], acc[0][ds_], 0, 0, 0);
            }
        }
    }

    if (qt < 16) {
        #pragma unroll
        for (int s = 0; s < 2; ++s) {
            const int base = s ? s1 : s0;
            #pragma unroll
            for (int rg = 0; rg < 4; ++rg) {
                const float inv = 1.0f / accl[s][rg];   // denom for q=quad*4+rg
                const size_t row = (size_t)(base + quad*4 + rg) * DMODEL + h * DK;
                #pragma unroll
                for (int ds_ = 0; ds_ < 4; ++ds_)
                    O[row + ds_*16 + l15] = (__bf16)(acc[s][ds_][rg] * inv);
            }
        }
    } else {
        const int unit = (h*16 + (qt - 16))*2 + g;
        const size_t pbase = (size_t)unit * 8192;   // 128 rows x 64 d fp32
        #pragma unroll
        for (int s = 0; s < 2; ++s) {
            #pragma unroll
            for (int rg = 0; rg < 4; ++rg) {
                const int lrow = s*64 + w*16 + quad*4 + rg;
                #pragma unroll
                for (int ds_ = 0; ds_ < 4; ++ds_)
                    part[pbase + lrow*64 + ds_*16 + l15] = acc[s][ds_][rg];
            }
            if (l15 == 0) {
                #pragma unroll
                for (int rg = 0; rg < 4; ++rg)
                    lpart[unit*128 + s*64 + w*16 + quad*4 + rg] = accl[s][rg];
            }
        }
    }
}

// ---------------------------------------------------------------------------
// Combine the two KV-chunk partials for qt in [16,32): O = (p0+p1)/(l0+l1).
// ---------------------------------------------------------------------------
__global__ __launch_bounds__(256)
void attn_combine(const float* __restrict__ part, const float* __restrict__ lpart,
                  __bf16* __restrict__ O)
{
    const int t = threadIdx.x;
    const int qtp = blockIdx.x;          // 0..15 -> qt = 16+qtp
    const int h = blockIdx.y;
    const int u0 = (h*16 + qtp)*2;
    const size_t b0 = (size_t)u0 * 8192;
    const size_t b1 = b0 + 8192;
    const int r  = t >> 1;               // 0..127 local row
    const int d0 = (t & 1) * 32;

    const float l = lpart[u0*128 + r] + lpart[(u0 + 1)*128 + r];
    const float inv = 1.0f / l;
    const size_t grow = (size_t)((16 + qtp)*128 + r) * DMODEL + h*64 + d0;
    #pragma unroll
    for (int i = 0; i < 4; ++i) {        // 4 groups of 8
        bf16x8 pk;
        #pragma unroll
        for (int j = 0; j < 2; ++j) {
            const float4 p0 = *reinterpret_cast<const float4*>(&part[b0 + r*64 + d0 + i*8 + j*4]);
            const float4 p1 = *reinterpret_cast<const float4*>(&part[b1 + r*64 + d0 + i*8 + j*4]);
            pk[j*4+0] = (__bf16)((p0.x + p1.x) * inv);
            pk[j*4+1] = (__bf16)((p0.y + p1.y) * inv);
            pk[j*4+2] = (__bf16)((p0.z + p1.z) * inv);
            pk[j*4+3] = (__bf16)((p0.w + p1.w) * inv);
        }
        *reinterpret_cast<bf16x8*>(&O[grow + i*8]) = pk;
    }
}

// ---------------------------------------------------------------------------
extern "C" void kernel_launch(void* const* d_in, const int* in_sizes, int n_in,
                              void* d_out, int out_size, void* d_ws, size_t ws_size,
                              hipStream_t stream) {
    const float* x  = (const float*)d_in[0];
    const float* Wq = (const float*)d_in[1];
    const float* bq = (const float*)d_in[2];
    const float* Wk = (const float*)d_in[3];
    const float* bk = (const float*)d_in[4];
    const float* Wv = (const float*)d_in[5];
    const float* bv = (const float*)d_in[6];
    const float* Wo = (const float*)d_in[7];
    const float* bo = (const float*)d_in[8];
    float* out = (float*)d_out;

    const size_t M1 = 1u << 20;
    __bf16* base = (__bf16*)d_ws;
    __bf16*    xb   = base;                          // 4M bf16
    __bf16*    Wcat = base + 4*M1;                   // Wq|Wk|Wv (3M bf16)
    __bf16*    Wob  = base + 7*M1;                   // 1M bf16
    _Float16*  Qh   = (_Float16*)(base + 8*M1);      // 4M fp16 each
    _Float16*  Kh   = (_Float16*)(base + 12*M1);
    _Float16*  Vth  = (_Float16*)(base + 16*M1);
    __bf16*    Ob   = base + 20*M1;                  // 4M bf16
    float*     lpart = (float*)(base + 24*M1);       // 512*128 fp32 = 256 KB
    float*     part  = out;                          // fp32 partials: exact 16 MB fit

    cvt_all<<<4096, 256, 0, stream>>>(x, Wq, Wk, Wv, Wo, base);
    gemm_qkv<<<dim3(24, 32), 256, 0, stream>>>(xb, Wcat, bq, bk, bv, Qh, Kh, Vth);
    attn_mfma<<<dim3(48, NH), 256, 0, stream>>>(Qh, Kh, Vth, Ob, part, lpart);
    attn_combine<<<dim3(16, NH), 256, 0, stream>>>(part, lpart, Ob);
    gemm_out<<<dim3(16, 32), 256, 0, stream>>>(Ob, Wob, bo, out);
}

// Round 4
// 219.982 us; speedup vs baseline: 1.4983x; 1.4983x over previous
//
#include <hip/hip_runtime.h>
#include <math.h>

#define SEQ 4096
#define DMODEL 1024
#define NH 16
#define DK 64
#define LDP 72   // padded LDS row (16-bit elems): conflict-free b64/b128 frag reads

typedef __bf16    bf16x8 __attribute__((ext_vector_type(8)));
typedef float     f32x4  __attribute__((ext_vector_type(4)));
typedef __fp16    fp16x2 __attribute__((ext_vector_type(2)));
typedef _Float16  h16x2  __attribute__((ext_vector_type(2)));
typedef _Float16  h16x4  __attribute__((ext_vector_type(4)));
typedef _Float16  h16x8  __attribute__((ext_vector_type(8)));

// global->LDS DMA, 16 B per lane; LDS dest = uniform base + lane*16 (no pad!)
#define GLOAD_LDS16(g, l) __builtin_amdgcn_global_load_lds(                     \
    (const __attribute__((address_space(1))) unsigned int*)(g),                 \
    (__attribute__((address_space(3))) unsigned int*)(l), 16, 0, 0)

// packed f32->f16 (RTZ), re-typed to _Float16x2
__device__ __forceinline__ h16x2 cvt_pk_h16(float a, float b) {
    fp16x2 r = __builtin_amdgcn_cvt_pkrtz(a, b);
    return __builtin_bit_cast(h16x2, r);
}

// raw v_exp_f32 (no denormal-guard expansion; inputs bounded)
#define EXP2R(x) __builtin_amdgcn_exp2f(x)

// ---------------------------------------------------------------------------
// Convert x (4M) + Wq/Wk/Wv/Wo (1M each) fp32 -> bf16 into contiguous ws.
// ---------------------------------------------------------------------------
__global__ __launch_bounds__(256)
void cvt_all(const float* __restrict__ x, const float* __restrict__ Wq,
             const float* __restrict__ Wk, const float* __restrict__ Wv,
             const float* __restrict__ Wo, __bf16* __restrict__ dst)
{
    const size_t M1 = 1u << 20;
    const size_t e = ((size_t)blockIdx.x * 256 + threadIdx.x) * 8;
    const float* src; size_t off;
    if      (e < 4*M1) { src = x;  off = e;        }
    else if (e < 5*M1) { src = Wq; off = e - 4*M1; }
    else if (e < 6*M1) { src = Wk; off = e - 5*M1; }
    else if (e < 7*M1) { src = Wv; off = e - 6*M1; }
    else               { src = Wo; off = e - 7*M1; }
    const float4 f0 = *reinterpret_cast<const float4*>(&src[off]);
    const float4 f1 = *reinterpret_cast<const float4*>(&src[off + 4]);
    bf16x8 pk;
    pk[0]=(__bf16)f0.x; pk[1]=(__bf16)f0.y; pk[2]=(__bf16)f0.z; pk[3]=(__bf16)f0.w;
    pk[4]=(__bf16)f1.x; pk[5]=(__bf16)f1.y; pk[6]=(__bf16)f1.z; pk[7]=(__bf16)f1.w;
    *reinterpret_cast<bf16x8*>(&dst[e]) = pk;
}

// ---------------------------------------------------------------------------
// 128x128 GEMM core with global_load_lds staging (XOR chunk swizzle).
// ---------------------------------------------------------------------------
__device__ __forceinline__ void gemm_core128(const __bf16* __restrict__ A,
                                             const __bf16* __restrict__ W,
                                             int m0, int n0, int t,
                                             __bf16* AsF, __bf16* BsF,
                                             f32x4 acc[4][4])
{
    const int w = t >> 6, lane = t & 63, l15 = lane & 15, quad = lane >> 4;
    const int wm = (w & 1) * 64, wn = (w >> 1) * 64;
    const int lr = lane >> 3, lc = lane & 7;
    for (int k0 = 0; k0 < DMODEL; k0 += 64) {
        __syncthreads();
        #pragma unroll
        for (int p = 0; p < 4; ++p) {
            const int n = w*4 + p;
            const int r = n*8 + lr;
            const int cl = lc ^ (r & 7);
            GLOAD_LDS16(&A[(size_t)(m0 + r) * DMODEL + k0 + cl*8], &AsF[n*512]);
            GLOAD_LDS16(&W[(size_t)(n0 + r) * DMODEL + k0 + cl*8], &BsF[n*512]);
        }
        __syncthreads();
        #pragma unroll
        for (int kb = 0; kb < 2; ++kb) {
            const int phys = ((kb*4 + quad) ^ (l15 & 7)) * 8;
            bf16x8 af[4], bfr[4];
            #pragma unroll
            for (int i = 0; i < 4; ++i) {
                af[i]  = *reinterpret_cast<const bf16x8*>(&AsF[(wm + i*16 + l15)*64 + phys]);
                bfr[i] = *reinterpret_cast<const bf16x8*>(&BsF[(wn + i*16 + l15)*64 + phys]);
            }
            #pragma unroll
            for (int ms = 0; ms < 4; ++ms)
                #pragma unroll
                for (int ns = 0; ns < 4; ++ns)
                    acc[ms][ns] = __builtin_amdgcn_mfma_f32_16x16x32_bf16(af[ms], bfr[ns], acc[ms][ns], 0, 0, 0);
        }
    }
}

// ---------------------------------------------------------------------------
// Fused QKV projection -> fp16. [0,1024)=Q scaled 0.125*log2e; [1024,2048)=K;
// [2048,3072)=V transposed Vt[d][s]. Q/K epilogue via per-wave LDS transpose.
// ---------------------------------------------------------------------------
__global__ __launch_bounds__(256, 3)
void gemm_qkv(const __bf16* __restrict__ xb, const __bf16* __restrict__ Wcat,
              const float* __restrict__ bq, const float* __restrict__ bk,
              const float* __restrict__ bv,
              _Float16* __restrict__ Qh, _Float16* __restrict__ Kh, _Float16* __restrict__ Vth)
{
    __shared__ __bf16 SM[4*64*LDP];      // staging uses first 32 KB
    __bf16* AsF = SM;
    __bf16* BsF = SM + 8192;
    const int t = threadIdx.x;
    const int n0g = blockIdx.x * 128;
    const int m0  = blockIdx.y * 128;
    const int which = n0g >> 10;
    const int n_in  = n0g & 1023;

    f32x4 acc[4][4] = {};
    gemm_core128(xb, Wcat, m0, n0g, t, AsF, BsF, acc);

    const int w = t >> 6, lane = t & 63, l15 = lane & 15, quad = lane >> 4;
    const int wm = (w & 1) * 64, wn = (w >> 1) * 64;
    const float* bias = (which == 0) ? bq : (which == 1) ? bk : bv;
    float br[4];
    #pragma unroll
    for (int ns = 0; ns < 4; ++ns) br[ns] = bias[n_in + wn + ns*16 + l15];

    if (which == 2) {
        #pragma unroll
        for (int ms = 0; ms < 4; ++ms)
            #pragma unroll
            for (int ns = 0; ns < 4; ++ns) {
                h16x4 pk;
                #pragma unroll
                for (int rg = 0; rg < 4; ++rg) pk[rg] = (_Float16)(acc[ms][ns][rg] + br[ns]);
                *reinterpret_cast<h16x4*>(
                    &Vth[(size_t)(n_in + wn + ns*16 + l15) * SEQ + m0 + wm + ms*16 + quad*4]) = pk;
            }
    } else {
        const float s = (which == 0) ? 0.1803368787f : 1.0f;  // 0.125 * log2(e)
        _Float16* C = (which == 0) ? Qh : Kh;
        __syncthreads();   // all waves done with staging LDS
        _Float16* tile = (_Float16*)SM + w * 64 * LDP;   // per-wave 64x72 region
        #pragma unroll
        for (int ms = 0; ms < 4; ++ms)
            #pragma unroll
            for (int ns = 0; ns < 4; ++ns)
                #pragma unroll
                for (int rg = 0; rg < 4; ++rg)
                    tile[(ms*16 + quad*4 + rg) * LDP + ns*16 + l15] =
                        (_Float16)((acc[ms][ns][rg] + br[ns]) * s);
        asm volatile("s_waitcnt lgkmcnt(0)" ::: "memory");   // same-wave drain
        const int er = lane >> 3, ec = (lane & 7) * 8;
        #pragma unroll
        for (int p = 0; p < 8; ++p) {
            const h16x8 v = *reinterpret_cast<const h16x8*>(&tile[(er + p*8) * LDP + ec]);
            *reinterpret_cast<h16x8*>(
                &C[(size_t)(m0 + wm + er + p*8) * DMODEL + n_in + wn + ec]) = v;
        }
    }
}

// ---------------------------------------------------------------------------
// 128x64 GEMM core with DMA staging, for the output projection.
// ---------------------------------------------------------------------------
__device__ __forceinline__ void gemm_core64(const __bf16* __restrict__ A,
                                            const __bf16* __restrict__ W,
                                            int m0, int n0, int t,
                                            __bf16* AsF, __bf16* BsF,
                                            f32x4 acc[2][4])
{
    const int w = t >> 6, lane = t & 63, l15 = lane & 15, quad = lane >> 4;
    const int lr = lane >> 3, lc = lane & 7;
    for (int k0 = 0; k0 < DMODEL; k0 += 64) {
        __syncthreads();
        #pragma unroll
        for (int p = 0; p < 4; ++p) {
            const int n = w*4 + p;
            const int r = n*8 + lr;
            const int cl = lc ^ (r & 7);
            GLOAD_LDS16(&A[(size_t)(m0 + r) * DMODEL + k0 + cl*8], &AsF[n*512]);
        }
        #pragma unroll
        for (int p = 0; p < 2; ++p) {
            const int n = w*2 + p;
            const int r = n*8 + lr;
            const int cl = lc ^ (r & 7);
            GLOAD_LDS16(&W[(size_t)(n0 + r) * DMODEL + k0 + cl*8], &BsF[n*512]);
        }
        __syncthreads();
        #pragma unroll
        for (int kb = 0; kb < 2; ++kb) {
            const int phys = ((kb*4 + quad) ^ (l15 & 7)) * 8;
            bf16x8 af0 = *reinterpret_cast<const bf16x8*>(&AsF[(w*32 + l15)*64 + phys]);
            bf16x8 af1 = *reinterpret_cast<const bf16x8*>(&AsF[(w*32 + 16 + l15)*64 + phys]);
            #pragma unroll
            for (int ns = 0; ns < 4; ++ns) {
                const bf16x8 bfr = *reinterpret_cast<const bf16x8*>(&BsF[(ns*16 + l15)*64 + phys]);
                acc[0][ns] = __builtin_amdgcn_mfma_f32_16x16x32_bf16(af0, bfr, acc[0][ns], 0, 0, 0);
                acc[1][ns] = __builtin_amdgcn_mfma_f32_16x16x32_bf16(af1, bfr, acc[1][ns], 0, 0, 0);
            }
        }
    }
}

__global__ __launch_bounds__(256, 4)
void gemm_out(const __bf16* __restrict__ Ob, const __bf16* __restrict__ Wob,
              const float* __restrict__ bo, float* __restrict__ out)
{
    __shared__ __bf16 AsF[128*64];
    __shared__ __bf16 BsF[64*64];
    const int t = threadIdx.x;
    const int n0 = blockIdx.x * 64;
    const int m0 = blockIdx.y * 128;

    f32x4 acc[2][4] = {};
    gemm_core64(Ob, Wob, m0, n0, t, AsF, BsF, acc);

    const int lane = t & 63, l15 = lane & 15, quad = lane >> 4, w = t >> 6;
    float br[4];
    #pragma unroll
    for (int ns = 0; ns < 4; ++ns) br[ns] = bo[n0 + ns*16 + l15];
    #pragma unroll
    for (int ms = 0; ms < 2; ++ms)
        #pragma unroll
        for (int ns = 0; ns < 4; ++ns)
            #pragma unroll
            for (int rg = 0; rg < 4; ++rg)
                out[(size_t)(m0 + w*32 + ms*16 + quad*4 + rg) * DMODEL + n0 + ns*16 + l15] =
                    acc[ms][ns][rg] + br[ns];
}

// ---------------------------------------------------------------------------
// Causal flash attention, V4 = V2 structure (double-buffered DMA LDS, one
// barrier/tile) + VALU cuts:
//   * raw v_exp_f32 via __builtin_amdgcn_exp2f (exp2f's libm lowering adds a
//     ~5-instr denormal guard per value; inputs here are bounded so raw is
//     exact enough).
//   * causal-mask cmp/cndmask chain hoisted behind the wave-uniform msk flag:
//     interior tiles (the common case) run zero mask VALU ops.
// Softmax: sum-only base-2, denominator via ones-B MFMA (accl row map = acc).
// Unit map (u in [0,48)), each CU's 3 units sum to 66 iterations:
//   u<16 : qt=16+u, g=0  (32 tiles)
//   u<32 : qt=u,    g=1  (qt in [16,32), 2qt-30 tiles, ascending)
//   u<48 : qt=47-u, g=0  single-chunk (2qt+2 tiles, descending)
// qt<16: normalize in-kernel -> bf16 Ob. qt>=16: fp32 partials -> part
// (d_out scratch, 512 units x 32 KB = exactly 16 MB) + row sums -> lpart.
// ---------------------------------------------------------------------------
__global__ __launch_bounds__(256, 3)
void attn_mfma(const _Float16* __restrict__ Q, const _Float16* __restrict__ K,
               const _Float16* __restrict__ Vt, __bf16* __restrict__ O,
               float* __restrict__ part, float* __restrict__ lpart)
{
    __shared__ _Float16 KsF[2][64*64];   // [key][d], chunk-XOR swizzled (DMA)
    __shared__ _Float16 VsF[2][64*64];   // [d][key], chunk-XOR swizzled (DMA)

    const int t = threadIdx.x;
    const int w = t >> 6;
    const int lane = t & 63, l15 = lane & 15, quad = lane >> 4;
    const int lr = lane >> 3, lc = lane & 7;
    const int h = blockIdx.y;
    const int u = blockIdx.x;
    int qt, g;
    if      (u < 16) { qt = 16 + u; g = 0; }
    else if (u < 32) { qt = u;      g = 1; }
    else             { qt = 47 - u; g = 0; }
    const int tstart = g * 32;
    const int tlast  = 2*qt + 1;
    const int tend   = (tlast < tstart + 31) ? tlast : (tstart + 31);
    const int s0 = qt*128 + w*16;        // slice0 row base
    const int s1 = s0 + 64;              // slice1 row base

    // Q B-frags (x32: lane n=q=l15 holds d=quad*8+j), both slices, loaded once.
    h16x8 bq8[2][2];
    #pragma unroll
    for (int kb = 0; kb < 2; ++kb) {
        bq8[0][kb] = *reinterpret_cast<const h16x8*>(
            &Q[(size_t)(s0 + l15) * DMODEL + h*DK + kb*32 + quad*8]);
        bq8[1][kb] = *reinterpret_cast<const h16x8*>(
            &Q[(size_t)(s1 + l15) * DMODEL + h*DK + kb*32 + quad*8]);
    }

    // Per-lane staging sources (XOR-pre-swizzled global addrs; dest is linear).
    const int cl = lc ^ lr;
    const int rA = (w*2 + 0)*8 + lr, rB = (w*2 + 1)*8 + lr;
    const int dA = (w*2 + 0)*512,   dB = (w*2 + 1)*512;
    const _Float16* kpA = &K [(size_t)(tstart*64 + rA) * DMODEL + h*DK + cl*8];
    const _Float16* kpB = &K [(size_t)(tstart*64 + rB) * DMODEL + h*DK + cl*8];
    const _Float16* vpA = &Vt[(size_t)(h*DK + rA) * SEQ + tstart*64 + cl*8];
    const _Float16* vpB = &Vt[(size_t)(h*DK + rB) * SEQ + tstart*64 + cl*8];

#define STAGE_KV(bi) do {                                     \
        GLOAD_LDS16(kpA, &KsF[bi][dA]);                       \
        GLOAD_LDS16(kpB, &KsF[bi][dB]);                       \
        GLOAD_LDS16(vpA, &VsF[bi][dA]);                       \
        GLOAD_LDS16(vpB, &VsF[bi][dB]);                       \
        kpA += (size_t)64*DMODEL; kpB += (size_t)64*DMODEL;   \
        vpA += 64; vpB += 64; } while (0)

    f32x4 acc[2][4] = {};        // [slice][dsub]; C: col=d=l15, row=q=quad*4+rg
    f32x4 accl[2] = {};          // denom rowsums via ones-MFMA (same row map)
    const h16x4 vone = {(_Float16)1.f, (_Float16)1.f, (_Float16)1.f, (_Float16)1.f};

    STAGE_KV(0);                 // prologue: stage tile tstart into buffer 0
    __syncthreads();             // drains prologue DMA (vmcnt) + barrier

    int pbuf = 0;
    for (int tk = tstart; tk <= tend; ++tk, pbuf ^= 1) {
        if (tk < tend) STAGE_KV(pbuf ^ 1);   // issue next tile's DMA first

        const int j0 = tk * 64;
        const bool act0 = (j0 <= s0 + 15);   // slice0 still in causal range
        const bool msk0 = (j0 + 63 > s0);    // wave-uniform
        const bool msk1 = (j0 + 63 > s1);    // wave-uniform
        const int rel0 = s0 - j0 + l15;
        const int rel1 = s1 - j0 + l15;

        // ---- S^T = K . Q^T (x32); K A-frags shared by both slices ----
        h16x4 ap[2][4];
        #pragma unroll
        for (int st = 0; st < 4; ++st) {
            const h16x8 ak0 = *reinterpret_cast<const h16x8*>(
                &KsF[pbuf][(st*16 + l15)*64 + ((quad ^ (l15 & 7)))*8]);
            const h16x8 ak1 = *reinterpret_cast<const h16x8*>(
                &KsF[pbuf][(st*16 + l15)*64 + (((4 + quad) ^ (l15 & 7)))*8]);
            // slice 1 (always active)
            {
                f32x4 cc = {0.f, 0.f, 0.f, 0.f};
                cc = __builtin_amdgcn_mfma_f32_16x16x32_f16(ak0, bq8[1][0], cc, 0, 0, 0);
                cc = __builtin_amdgcn_mfma_f32_16x16x32_f16(ak1, bq8[1][1], cc, 0, 0, 0);
                float pv[4];
                if (msk1) {
                    #pragma unroll
                    for (int rg = 0; rg < 4; ++rg) {
                        const float e = EXP2R(cc[rg]);
                        pv[rg] = (st*16 + quad*4 + rg > rel1) ? 0.f : e;
                    }
                } else {
                    #pragma unroll
                    for (int rg = 0; rg < 4; ++rg) pv[rg] = EXP2R(cc[rg]);
                }
                const h16x2 lo = cvt_pk_h16(pv[0], pv[1]);
                const h16x2 hi = cvt_pk_h16(pv[2], pv[3]);
                ap[1][st] = (h16x4){lo[0], lo[1], hi[0], hi[1]};
                accl[1] = __builtin_amdgcn_mfma_f32_16x16x16f16(ap[1][st], vone, accl[1], 0, 0, 0);
            }
            // slice 0
            if (act0) {
                f32x4 cc = {0.f, 0.f, 0.f, 0.f};
                cc = __builtin_amdgcn_mfma_f32_16x16x32_f16(ak0, bq8[0][0], cc, 0, 0, 0);
                cc = __builtin_amdgcn_mfma_f32_16x16x32_f16(ak1, bq8[0][1], cc, 0, 0, 0);
                float pv[4];
                if (msk0) {
                    #pragma unroll
                    for (int rg = 0; rg < 4; ++rg) {
                        const float e = EXP2R(cc[rg]);
                        pv[rg] = (st*16 + quad*4 + rg > rel0) ? 0.f : e;
                    }
                } else {
                    #pragma unroll
                    for (int rg = 0; rg < 4; ++rg) pv[rg] = EXP2R(cc[rg]);
                }
                const h16x2 lo = cvt_pk_h16(pv[0], pv[1]);
                const h16x2 hi = cvt_pk_h16(pv[2], pv[3]);
                ap[0][st] = (h16x4){lo[0], lo[1], hi[0], hi[1]};
                accl[0] = __builtin_amdgcn_mfma_f32_16x16x16f16(ap[0][st], vone, accl[0], 0, 0, 0);
            }
        }

        // ---- O^ += P . V (x16); V B-frags shared by both slices ----
        // logical [d=ds*16+l15][key=st*16+quad*4 ..+4): phys 16B chunk =
        // (st*2 + (quad>>1)) ^ (d & 7), 8B half selected by quad&1.
        #pragma unroll
        for (int ds_ = 0; ds_ < 4; ++ds_) {
            #pragma unroll
            for (int st = 0; st < 4; ++st) {
                const h16x4 bv = *reinterpret_cast<const h16x4*>(
                    &VsF[pbuf][(ds_*16 + l15)*64 +
                               (((st*2 + (quad >> 1)) ^ (l15 & 7)))*8 + (quad & 1)*4]);
                acc[1][ds_] = __builtin_amdgcn_mfma_f32_16x16x16f16(ap[1][st], bv, acc[1][ds_], 0, 0, 0);
                if (act0)
                    acc[0][ds_] = __builtin_amdgcn_mfma_f32_16x16x16f16(ap[0][st], bv, acc[0][ds_], 0, 0, 0);
            }
        }
        __syncthreads();   // readers of pbuf done + next-tile DMA drained
    }
#undef STAGE_KV

    if (qt < 16) {
        #pragma unroll
        for (int s = 0; s < 2; ++s) {
            const int base = s ? s1 : s0;
            #pragma unroll
            for (int rg = 0; rg < 4; ++rg) {
                const float inv = 1.0f / accl[s][rg];   // denom for q=quad*4+rg
                const size_t row = (size_t)(base + quad*4 + rg) * DMODEL + h * DK;
                #pragma unroll
                for (int ds_ = 0; ds_ < 4; ++ds_)
                    O[row + ds_*16 + l15] = (__bf16)(acc[s][ds_][rg] * inv);
            }
        }
    } else {
        const int unit = (h*16 + (qt - 16))*2 + g;
        const size_t pbase = (size_t)unit * 8192;   // 128 rows x 64 d fp32
        #pragma unroll
        for (int s = 0; s < 2; ++s) {
            #pragma unroll
            for (int rg = 0; rg < 4; ++rg) {
                const int lrow = s*64 + w*16 + quad*4 + rg;
                #pragma unroll
                for (int ds_ = 0; ds_ < 4; ++ds_)
                    part[pbase + lrow*64 + ds_*16 + l15] = acc[s][ds_][rg];
            }
            if (l15 == 0) {
                #pragma unroll
                for (int rg = 0; rg < 4; ++rg)
                    lpart[unit*128 + s*64 + w*16 + quad*4 + rg] = accl[s][rg];
            }
        }
    }
}

// ---------------------------------------------------------------------------
// Combine the two KV-chunk partials for qt in [16,32): O = (p0+p1)/(l0+l1).
// ---------------------------------------------------------------------------
__global__ __launch_bounds__(256)
void attn_combine(const float* __restrict__ part, const float* __restrict__ lpart,
                  __bf16* __restrict__ O)
{
    const int t = threadIdx.x;
    const int qtp = blockIdx.x;          // 0..15 -> qt = 16+qtp
    const int h = blockIdx.y;
    const int u0 = (h*16 + qtp)*2;
    const size_t b0 = (size_t)u0 * 8192;
    const size_t b1 = b0 + 8192;
    const int r  = t >> 1;               // 0..127 local row
    const int d0 = (t & 1) * 32;

    const float l = lpart[u0*128 + r] + lpart[(u0 + 1)*128 + r];
    const float inv = 1.0f / l;
    const size_t grow = (size_t)((16 + qtp)*128 + r) * DMODEL + h*64 + d0;
    #pragma unroll
    for (int i = 0; i < 4; ++i) {        // 4 groups of 8
        bf16x8 pk;
        #pragma unroll
        for (int j = 0; j < 2; ++j) {
            const float4 p0 = *reinterpret_cast<const float4*>(&part[b0 + r*64 + d0 + i*8 + j*4]);
            const float4 p1 = *reinterpret_cast<const float4*>(&part[b1 + r*64 + d0 + i*8 + j*4]);
            pk[j*4+0] = (__bf16)((p0.x + p1.x) * inv);
            pk[j*4+1] = (__bf16)((p0.y + p1.y) * inv);
            pk[j*4+2] = (__bf16)((p0.z + p1.z) * inv);
            pk[j*4+3] = (__bf16)((p0.w + p1.w) * inv);
        }
        *reinterpret_cast<bf16x8*>(&O[grow + i*8]) = pk;
    }
}

// ---------------------------------------------------------------------------
extern "C" void kernel_launch(void* const* d_in, const int* in_sizes, int n_in,
                              void* d_out, int out_size, void* d_ws, size_t ws_size,
                              hipStream_t stream) {
    const float* x  = (const float*)d_in[0];
    const float* Wq = (const float*)d_in[1];
    const float* bq = (const float*)d_in[2];
    const float* Wk = (const float*)d_in[3];
    const float* bk = (const float*)d_in[4];
    const float* Wv = (const float*)d_in[5];
    const float* bv = (const float*)d_in[6];
    const float* Wo = (const float*)d_in[7];
    const float* bo = (const float*)d_in[8];
    float* out = (float*)d_out;

    const size_t M1 = 1u << 20;
    __bf16* base = (__bf16*)d_ws;
    __bf16*    xb   = base;                          // 4M bf16
    __bf16*    Wcat = base + 4*M1;                   // Wq|Wk|Wv (3M bf16)
    __bf16*    Wob  = base + 7*M1;                   // 1M bf16
    _Float16*  Qh   = (_Float16*)(base + 8*M1);      // 4M fp16 each
    _Float16*  Kh   = (_Float16*)(base + 12*M1);
    _Float16*  Vth  = (_Float16*)(base + 16*M1);
    __bf16*    Ob   = base + 20*M1;                  // 4M bf16
    float*     lpart = (float*)(base + 24*M1);       // 512*128 fp32 = 256 KB
    float*     part  = out;                          // fp32 partials: exact 16 MB fit

    cvt_all<<<4096, 256, 0, stream>>>(x, Wq, Wk, Wv, Wo, base);
    gemm_qkv<<<dim3(24, 32), 256, 0, stream>>>(xb, Wcat, bq, bk, bv, Qh, Kh, Vth);
    attn_mfma<<<dim3(48, NH), 256, 0, stream>>>(Qh, Kh, Vth, Ob, part, lpart);
    attn_combine<<<dim3(16, NH), 256, 0, stream>>>(part, lpart, Ob);
    gemm_out<<<dim3(16, 32), 256, 0, stream>>>(Ob, Wob, bo, out);
}